// Round 8
// baseline (409.092 us; speedup 1.0000x reference)
//
#include <hip/hip_runtime.h>
#include <hip/hip_bf16.h>
#include <math.h>

constexpr int NB   = 4;
constexpr int LL   = 8192;
constexpr int DD   = 256;
constexpr int NH   = 8;
constexpr int WNN  = 9;

constexpr int CW   = 16;        // windows per block
constexpr int RSN  = CW + 8;    // 24 staged halo rows
constexpr int SST  = 260;       // bf16 LDS row stride for q/k/v/pos (8B-aligned rows, bank spread)
constexpr int XST  = 264;       // stride for xs/ctx/ar tiles (16B-aligned rows)

typedef __attribute__((ext_vector_type(8))) short bf16x8;
typedef __attribute__((ext_vector_type(4))) float f32x4;

__device__ inline short f2bf(float f) {
  __hip_bfloat16 h = __float2bfloat16(f);
  short s; __builtin_memcpy(&s, &h, 2); return s;
}
__device__ inline float bf2f(short s) {
  unsigned u = ((unsigned)(unsigned short)s) << 16;
  float f; __builtin_memcpy(&f, &u, 4); return f;
}

// ---------------- prep (round-7 verbatim, proven): transposes + Wout conv + pos projection ----------------
__global__ __launch_bounds__(256) void prep_all(
    const float* __restrict__ Wq, const float* __restrict__ Wk, const float* __restrict__ Wv,
    const float* __restrict__ Wo, const float* __restrict__ Wout, const float* __restrict__ pos,
    short* __restrict__ WqT, short* __restrict__ WkT, short* __restrict__ WvT,
    short* __restrict__ WoT, short* __restrict__ WoutB,
    short* __restrict__ PQb, short* __restrict__ PKb, short* __restrict__ PVb) {
  __shared__ float sm[64 * 65];
  const int t = threadIdx.x, b = blockIdx.x;
  if (b < 64) {
    const int wi = b >> 4, tile = b & 15;
    const int r0 = (tile >> 2) * 64, c0 = (tile & 3) * 64;
    const float* W = (wi == 0) ? Wq : (wi == 1) ? Wk : (wi == 2) ? Wv : Wo;
    short* T = (wi == 0) ? WqT : (wi == 1) ? WkT : (wi == 2) ? WvT : WoT;
    const int tr = t >> 6, tc = t & 63;
#pragma unroll
    for (int i = 0; i < 16; ++i) {
      int r = tr + i * 4;
      sm[r * 65 + tc] = W[(size_t)(r0 + r) * 256 + c0 + tc];
    }
    __syncthreads();
#pragma unroll
    for (int i = 0; i < 16; ++i) {
      int cj = tr + i * 4;
      T[(size_t)(c0 + cj) * 256 + r0 + tc] = f2bf(sm[tc * 65 + cj]);
    }
  } else if (b < 68) {
    const int idx = b - 64;
    for (int i = t; i < 4096; i += 256) {
      float4 v = *(const float4*)(Wout + ((size_t)idx * 4096 + i) * 4);
      short4 o; o.x = f2bf(v.x); o.y = f2bf(v.y); o.z = f2bf(v.z); o.w = f2bf(v.w);
      *(short4*)(WoutB + ((size_t)idx * 4096 + i) * 4) = o;
    }
  } else {
    const int wh = b - 68;
    const float* W = (wh == 0) ? Wq : (wh == 1) ? Wk : Wv;
    short* P = (wh == 0) ? PQb : (wh == 1) ? PKb : PVb;
    for (int i = t; i < WNN * 256; i += 256) sm[i] = pos[i];
    __syncthreads();
    float a[WNN];
#pragma unroll
    for (int w = 0; w < WNN; ++w) a[w] = 0.f;
    for (int d = 0; d < 256; ++d) {
      float wv = W[(size_t)d * 256 + t];
#pragma unroll
      for (int w = 0; w < WNN; ++w) a[w] += sm[w * 256 + d] * wv;
    }
#pragma unroll
    for (int w = 0; w < WNN; ++w) P[w * 256 + t] = f2bf(a[w]);
  }
}

// ---------------- mega: x -> QKV(LDS) -> windowed attn -> ctx -> Wo+LN1 -> Wout+LN2 -> relu ----------------
__global__ __launch_bounds__(256) void mega(
    const float* __restrict__ x,
    const short* __restrict__ WT0, const short* __restrict__ WT1, const short* __restrict__ WT2,
    const short* __restrict__ WoT, const short* __restrict__ WoutB,
    const short* __restrict__ PQb, const short* __restrict__ PKb, const short* __restrict__ PVb,
    const float* __restrict__ bo,
    const float* __restrict__ g1, const float* __restrict__ b1,
    const float* __restrict__ g2, const float* __restrict__ b2,
    float* __restrict__ out) {
  __shared__ short xs[32 * XST];              // phase1: x tile (rows 24..31 zero); later rows0-15 ctx, rows16-31 ar
  __shared__ short sq[RSN * SST];
  __shared__ short sk[RSN * SST];
  __shared__ short sv[RSN * SST];
  __shared__ short pq[WNN * SST];
  __shared__ short pk[WNN * SST];
  __shared__ short pv[WNN * SST];
  __shared__ float g1s[256], b1s[256], g2s[256], b2s[256], bos[256];
  __shared__ float ws1[16][4], ws2[16][4], msh[16], rsh[16];

  const int t = threadIdx.x, w = t >> 6, lane = t & 63, q = lane >> 4, m = lane & 15;
  const int nblk = LL / CW;
  const int bb = blockIdx.x / nblk;
  const int n0 = (blockIdx.x % nblk) * CW;
  const size_t rowg0 = (size_t)bb * LL + n0;   // first output row (global)

  g1s[t] = g1[t]; b1s[t] = b1[t]; g2s[t] = g2[t]; b2s[t] = b2[t]; bos[t] = bo[t];

  // ---- stage x rows [n0-4, n0+20) -> xs rows 0..23 bf16; rows 24..31 zero ----
#pragma unroll
  for (int i = 0; i < 8; ++i) {
    int idx = t + i * 256;                 // 32 rows x 64 groups
    int r = idx >> 6, c4 = (idx & 63) * 4;
    int j = n0 - 4 + r;
    float4 v = {0.f, 0.f, 0.f, 0.f};
    if (r < RSN && j >= 0 && j < LL) v = *(const float4*)(x + ((size_t)bb * LL + j) * DD + c4);
    short4 o; o.x = f2bf(v.x); o.y = f2bf(v.y); o.z = f2bf(v.z); o.w = f2bf(v.w);
    *(short4*)&xs[r * XST + c4] = o;
  }
  // ---- stage pos projections ----
#pragma unroll
  for (int i = 0; i < 3; ++i) {
    int idx = t + i * 256;
    if (idx < WNN * 64) {
      int r = idx >> 6, c4 = (idx & 63) * 4;
      *(short4*)&pq[r * SST + c4] = *(const short4*)(PQb + r * DD + c4);
      *(short4*)&pk[r * SST + c4] = *(const short4*)(PKb + r * DD + c4);
      *(short4*)&pv[r * SST + c4] = *(const short4*)(PVb + r * DD + c4);
    }
  }
  __syncthreads();

  // ---- phase 1: QKV via MFMA, outputs straight to LDS (q/k/v never touch HBM) ----
  {
    f32x4 acc[3][2][4];
#pragma unroll
    for (int bu = 0; bu < 3; ++bu)
#pragma unroll
      for (int i = 0; i < 2; ++i)
#pragma unroll
        for (int j = 0; j < 4; ++j) acc[bu][i][j] = (f32x4){0.f, 0.f, 0.f, 0.f};
#pragma unroll
    for (int kk = 0; kk < 8; ++kk) {
      bf16x8 a[2];
#pragma unroll
      for (int i = 0; i < 2; ++i) a[i] = *(const bf16x8*)&xs[(i * 16 + m) * XST + kk * 32 + q * 8];
#pragma unroll
      for (int bu = 0; bu < 3; ++bu) {
        const short* WT = (bu == 0) ? WT0 : (bu == 1) ? WT1 : WT2;
#pragma unroll
        for (int j = 0; j < 4; ++j) {
          bf16x8 bbf = *(const bf16x8*)(WT + (size_t)(w * 64 + j * 16 + m) * 256 + kk * 32 + q * 8);
#pragma unroll
          for (int i = 0; i < 2; ++i)
            acc[bu][i][j] = __builtin_amdgcn_mfma_f32_16x16x32_bf16(a[i], bbf, acc[bu][i][j], 0, 0, 0);
        }
      }
    }
#pragma unroll
    for (int bu = 0; bu < 3; ++bu) {
      short* S = (bu == 0) ? sq : (bu == 1) ? sk : sv;
#pragma unroll
      for (int i = 0; i < 2; ++i)
#pragma unroll
        for (int j = 0; j < 4; ++j)
#pragma unroll
          for (int r = 0; r < 4; ++r) {
            int rl = i * 16 + q * 4 + r;
            if (rl < RSN) S[rl * SST + w * 64 + j * 16 + m] = f2bf(acc[bu][i][j][r]);
          }
    }
  }
  __syncthreads();

  // ---- phase 2: scores; thread = (window n, head h, half) ----
  const int n = t >> 4, h = (t >> 1) & 7, half = t & 1;
  const int so = h * 32 + half * 16;      // this thread's 16-col slice
  float sc[WNN][WNN];
#pragma unroll
  for (int qi = 0; qi < WNN; ++qi)
#pragma unroll
    for (int ki = 0; ki < WNN; ++ki) sc[qi][ki] = 0.f;
#pragma unroll
  for (int c = 0; c < 4; ++c) {
    const int off = so + c * 4;
    float qv[WNN][4], kv[WNN][4];
#pragma unroll
    for (int r = 0; r < WNN; ++r) {
      short4 xa = *(const short4*)&sq[(n + r) * SST + off];
      short4 pa = *(const short4*)&pq[r * SST + off];
      qv[r][0] = bf2f(xa.x) + bf2f(pa.x);
      qv[r][1] = bf2f(xa.y) + bf2f(pa.y);
      qv[r][2] = bf2f(xa.z) + bf2f(pa.z);
      qv[r][3] = bf2f(xa.w) + bf2f(pa.w);
      short4 xb = *(const short4*)&sk[(n + r) * SST + off];
      short4 pb = *(const short4*)&pk[r * SST + off];
      kv[r][0] = bf2f(xb.x) + bf2f(pb.x);
      kv[r][1] = bf2f(xb.y) + bf2f(pb.y);
      kv[r][2] = bf2f(xb.z) + bf2f(pb.z);
      kv[r][3] = bf2f(xb.w) + bf2f(pb.w);
    }
#pragma unroll
    for (int qi = 0; qi < WNN; ++qi)
#pragma unroll
      for (int ki = 0; ki < WNN; ++ki)
        sc[qi][ki] += qv[qi][0] * kv[ki][0] + qv[qi][1] * kv[ki][1] +
                      qv[qi][2] * kv[ki][2] + qv[qi][3] * kv[ki][3];
  }
  // cross-half reduction (lanes t, t^1 hold the two 16-dim partials)
#pragma unroll
  for (int qi = 0; qi < WNN; ++qi)
#pragma unroll
    for (int ki = 0; ki < WNN; ++ki)
      sc[qi][ki] += __shfl_xor(sc[qi][ki], 1, 64);

  float cs[WNN];
#pragma unroll
  for (int ki = 0; ki < WNN; ++ki) cs[ki] = 0.f;
  const float scale = 0.17677669529663687f;  // 1/sqrt(32)
#pragma unroll
  for (int qi = 0; qi < WNN; ++qi) {
    float mx = sc[qi][0];
#pragma unroll
    for (int ki = 1; ki < WNN; ++ki) mx = fmaxf(mx, sc[qi][ki]);
    float e[WNN], sum = 0.f;
#pragma unroll
    for (int ki = 0; ki < WNN; ++ki) { e[ki] = __expf((sc[qi][ki] - mx) * scale); sum += e[ki]; }
    float inv = 1.f / sum;
#pragma unroll
    for (int ki = 0; ki < WNN; ++ki) cs[ki] += e[ki] * inv;
  }

  // ---- phase 3: ctx for this thread's 16 cols -> xs rows 0..15 (bf16) ----
#pragma unroll
  for (int c = 0; c < 4; ++c) {
    const int off = so + c * 4;
    float o0 = 0.f, o1 = 0.f, o2 = 0.f, o3 = 0.f;
#pragma unroll
    for (int ki = 0; ki < WNN; ++ki) {
      short4 xv4 = *(const short4*)&sv[(n + ki) * SST + off];
      short4 pv4 = *(const short4*)&pv[ki * SST + off];
      float wt = cs[ki];
      o0 += wt * (bf2f(xv4.x) + bf2f(pv4.x));
      o1 += wt * (bf2f(xv4.y) + bf2f(pv4.y));
      o2 += wt * (bf2f(xv4.z) + bf2f(pv4.z));
      o3 += wt * (bf2f(xv4.w) + bf2f(pv4.w));
    }
    short4 os; os.x = f2bf(o0); os.y = f2bf(o1); os.z = f2bf(o2); os.w = f2bf(o3);
    *(short4*)&xs[n * XST + off] = os;
  }
  __syncthreads();

  // ---- phase 4: out stage, M=16 ----
  {
    f32x4 acc1[4];
#pragma unroll
    for (int j = 0; j < 4; ++j) acc1[j] = (f32x4){0.f, 0.f, 0.f, 0.f};
#pragma unroll
    for (int kk = 0; kk < 8; ++kk) {
      bf16x8 a = *(const bf16x8*)&xs[m * XST + kk * 32 + q * 8];
#pragma unroll
      for (int j = 0; j < 4; ++j) {
        bf16x8 bbf = *(const bf16x8*)(WoT + (size_t)(w * 64 + j * 16 + m) * 256 + kk * 32 + q * 8);
        acc1[j] = __builtin_amdgcn_mfma_f32_16x16x32_bf16(a, bbf, acc1[j], 0, 0, 0);
      }
    }
    // + skip(x), LN1 stats
    float s1[4], s2[4];
#pragma unroll
    for (int r = 0; r < 4; ++r) {
      float a0 = 0.f, b0 = 0.f;
#pragma unroll
      for (int j = 0; j < 4; ++j) {
        int col = w * 64 + j * 16 + m;
        float v = acc1[j][r] + x[(rowg0 + q * 4 + r) * 256 + col];
        acc1[j][r] = v; a0 += v; b0 += v * v;
      }
      s1[r] = a0; s2[r] = b0;
    }
#pragma unroll
    for (int r = 0; r < 4; ++r)
#pragma unroll
      for (int msk = 1; msk < 16; msk <<= 1) {
        s1[r] += __shfl_xor(s1[r], msk, 64);
        s2[r] += __shfl_xor(s2[r], msk, 64);
      }
    if (m == 0) {
#pragma unroll
      for (int r = 0; r < 4; ++r) { ws1[q * 4 + r][w] = s1[r]; ws2[q * 4 + r][w] = s2[r]; }
    }
    __syncthreads();
    if (t < 16) {
      float a0 = 0.f, b0 = 0.f;
#pragma unroll
      for (int ww = 0; ww < 4; ++ww) { a0 += ws1[t][ww]; b0 += ws2[t][ww]; }
      float mean = a0 * (1.f / 256.f);
      float var = b0 * (1.f / 256.f) - mean * mean;
      msh[t] = mean; rsh[t] = rsqrtf(var + 1e-5f);
    }
    __syncthreads();
    // normalize -> ar (xs rows 16..31)
#pragma unroll
    for (int r = 0; r < 4; ++r) {
      int R = q * 4 + r;
      float mean = msh[R], rst = rsh[R];
#pragma unroll
      for (int j = 0; j < 4; ++j) {
        int col = w * 64 + j * 16 + m;
        float v = (acc1[j][r] - mean) * rst * g1s[col] + b1s[col];
        xs[(16 + R) * XST + col] = f2bf(v);
      }
    }
    __syncthreads();

    f32x4 acc2[4];
#pragma unroll
    for (int j = 0; j < 4; ++j) acc2[j] = (f32x4){0.f, 0.f, 0.f, 0.f};
#pragma unroll
    for (int kk = 0; kk < 8; ++kk) {
      bf16x8 a = *(const bf16x8*)&xs[(16 + m) * XST + kk * 32 + q * 8];
#pragma unroll
      for (int j = 0; j < 4; ++j) {
        bf16x8 bbf = *(const bf16x8*)(WoutB + (size_t)(w * 64 + j * 16 + m) * 256 + kk * 32 + q * 8);
        acc2[j] = __builtin_amdgcn_mfma_f32_16x16x32_bf16(a, bbf, acc2[j], 0, 0, 0);
      }
    }
    // + bias + residual(ar), LN2 stats
#pragma unroll
    for (int r = 0; r < 4; ++r) {
      int R = q * 4 + r;
      float a0 = 0.f, b0 = 0.f;
#pragma unroll
      for (int j = 0; j < 4; ++j) {
        int col = w * 64 + j * 16 + m;
        float v = acc2[j][r] + bos[col] + bf2f(xs[(16 + R) * XST + col]);
        acc2[j][r] = v; a0 += v; b0 += v * v;
      }
      s1[r] = a0; s2[r] = b0;
    }
#pragma unroll
    for (int r = 0; r < 4; ++r)
#pragma unroll
      for (int msk = 1; msk < 16; msk <<= 1) {
        s1[r] += __shfl_xor(s1[r], msk, 64);
        s2[r] += __shfl_xor(s2[r], msk, 64);
      }
    if (m == 0) {
#pragma unroll
      for (int r = 0; r < 4; ++r) { ws1[q * 4 + r][w] = s1[r]; ws2[q * 4 + r][w] = s2[r]; }
    }
    __syncthreads();
    if (t < 16) {
      float a0 = 0.f, b0 = 0.f;
#pragma unroll
      for (int ww = 0; ww < 4; ++ww) { a0 += ws1[t][ww]; b0 += ws2[t][ww]; }
      float mean = a0 * (1.f / 256.f);
      float var = b0 * (1.f / 256.f) - mean * mean;
      msh[t] = mean; rsh[t] = rsqrtf(var + 1e-5f);
    }
    __syncthreads();
#pragma unroll
    for (int r = 0; r < 4; ++r) {
      int R = q * 4 + r;
      float mean = msh[R], rst = rsh[R];
#pragma unroll
      for (int j = 0; j < 4; ++j) {
        int col = w * 64 + j * 16 + m;
        float v = (acc2[j][r] - mean) * rst * g2s[col] + b2s[col];
        out[(rowg0 + R) * 256 + col] = fmaxf(v, 0.f);
      }
    }
  }
}

extern "C" void kernel_launch(void* const* d_in, const int* in_sizes, int n_in,
                              void* d_out, int out_size, void* d_ws, size_t ws_size,
                              hipStream_t stream) {
  const float* x    = (const float*)d_in[0];
  const float* Wq   = (const float*)d_in[1];
  const float* Wk   = (const float*)d_in[2];
  const float* Wv   = (const float*)d_in[3];
  const float* Wo   = (const float*)d_in[4];
  const float* pos  = (const float*)d_in[5];
  const float* Wout = (const float*)d_in[6];
  const float* bo   = (const float*)d_in[7];
  const float* g1   = (const float*)d_in[8];
  const float* b1   = (const float*)d_in[9];
  const float* g2   = (const float*)d_in[10];
  const float* b2   = (const float*)d_in[11];
  float* out = (float*)d_out;

  char* wsb = (char*)d_ws;
  short* WqT   = (short*)wsb; wsb += 65536 * 2;
  short* WkT   = (short*)wsb; wsb += 65536 * 2;
  short* WvT   = (short*)wsb; wsb += 65536 * 2;
  short* WoT   = (short*)wsb; wsb += 65536 * 2;
  short* WoutB = (short*)wsb; wsb += 65536 * 2;
  short* PQb = (short*)wsb; wsb += WNN * DD * 2;
  short* PKb = (short*)wsb; wsb += WNN * DD * 2;
  short* PVb = (short*)wsb; wsb += WNN * DD * 2;

  prep_all<<<71, 256, 0, stream>>>(Wq, Wk, Wv, Wo, Wout, pos,
                                   WqT, WkT, WvT, WoT, WoutB, PQb, PKb, PVb);
  mega<<<NB * (LL / CW), 256, 0, stream>>>(x, WqT, WkT, WvT, WoT, WoutB,
                                           PQb, PKb, PVb, bo, g1, b1, g2, b2, out);
}